// Round 3
// baseline (116.072 us; speedup 1.0000x reference)
//
#include <hip/hip_runtime.h>

// EmbedDNF: B=128, IN_F=256, HID=512, OUT=128, E=8 (fp32, e innermost everywhere)
//
// impl = 1 - w*(1-xnor) = A + x*Bv with A = 1 - w*s, Bv = 2*w*s - w
// H[b,h,e]  = prod_i (A[i,h,e] + x[b,i,e]*Bv[i,h,e])
// out[b,o,e] = 1 - prod_h (1 - dw[h,o,e]*H[b,h,e])
//
// ws: H [128][512][8] fp32 (2 MB)

static inline __device__ float2 f2mul(float2 a, float2 b) {
    return make_float2(a.x * b.x, a.y * b.y);
}
static inline __device__ float2 f2fma(float2 a, float2 b, float2 c) {
    return make_float2(fmaf(a.x, b.x, c.x), fmaf(a.y, b.y, c.y));
}
// 1 - d*h
static inline __device__ float2 f2nfma1(float2 d, float2 h) {
    return make_float2(fmaf(-d.x, h.x, 1.0f), fmaf(-d.y, h.y, 1.0f));
}

// ---------------------------------------------------------------------------
// Stage 1. Grid 1024 = 16 bp (8 b) x 64 hg (8 h). Block 256 = 4 hl (2 h) x
// 4 eg (2 e) x 16 ck (16 i). Thread tile 8b x 2h x 2e (float2 over e).
// Lane-traffic 3 B/fma (w/s amortized x8 over b, x amortized x2 over h).
// i-partials combined in-block via LDS [ck][512 out] pitch 520.
// ---------------------------------------------------------------------------
__global__ __launch_bounds__(256, 4) void k_stage1(
    const float* __restrict__ in,   // [128][256][8]
    const float* __restrict__ cw,   // [256][512][8]
    const float* __restrict__ cs,   // [256][512][8]
    float* __restrict__ Hout)       // [128][512][8]
{
    __shared__ float lds[16 * 520];          // 33.3 KB
    const int t  = threadIdx.x;
    const int hl = t & 3;
    const int eg = (t >> 2) & 3;
    const int ck = t >> 4;
    const int bp = blockIdx.x & 15;
    const int hg = blockIdx.x >> 4;
    const int b0 = bp * 8;
    const int h0 = hg * 8 + hl * 2;          // this thread's first h
    const int e0 = eg * 2;
    const int i0 = ck * 16;

    float2 acc[8][2];
    #pragma unroll
    for (int b = 0; b < 8; ++b) {
        acc[b][0] = make_float2(1.0f, 1.0f);
        acc[b][1] = make_float2(1.0f, 1.0f);
    }

    const float* pw = cw + i0 * 4096 + h0 * 8 + e0;
    const float* ps = cs + i0 * 4096 + h0 * 8 + e0;
    const float* px = in + b0 * 2048 + i0 * 8 + e0;

    #pragma unroll 4
    for (int ii = 0; ii < 16; ++ii) {
        const float2 w0 = *(const float2*)(pw);
        const float2 w1 = *(const float2*)(pw + 8);
        const float2 s0 = *(const float2*)(ps);
        const float2 s1 = *(const float2*)(ps + 8);
        pw += 4096; ps += 4096;
        const float2 p0 = f2mul(w0, s0);
        const float2 p1 = f2mul(w1, s1);
        const float2 A0 = make_float2(1.0f - p0.x, 1.0f - p0.y);
        const float2 A1 = make_float2(1.0f - p1.x, 1.0f - p1.y);
        const float2 B0 = make_float2(p0.x + p0.x - w0.x, p0.y + p0.y - w0.y);
        const float2 B1 = make_float2(p1.x + p1.x - w1.x, p1.y + p1.y - w1.y);
        #pragma unroll
        for (int b = 0; b < 8; ++b) {
            const float2 xv = *(const float2*)(px + b * 2048);
            acc[b][0] = f2mul(acc[b][0], f2fma(xv, B0, A0));
            acc[b][1] = f2mul(acc[b][1], f2fma(xv, B1, A1));
        }
        px += 8;
    }

    // partials -> LDS: out = b*64 + hloc*8 + e  (hloc = hl*2+hh in [0,8))
    #pragma unroll
    for (int b = 0; b < 8; ++b) {
        #pragma unroll
        for (int hh = 0; hh < 2; ++hh) {
            const int out = b * 64 + (hl * 2 + hh) * 8 + e0;
            *(float2*)&lds[ck * 520 + out] = acc[b][hh];
        }
    }
    __syncthreads();

    // combine 16 ck, 512 outs -> 1 float2 per thread; contiguous global store
    {
        const int o2 = t * 2;
        float2 m = *(const float2*)&lds[o2];
        #pragma unroll
        for (int c = 1; c < 16; ++c)
            m = f2mul(m, *(const float2*)&lds[c * 520 + o2]);
        const int b = o2 >> 6;
        const int rem = o2 & 63;             // hloc*8 + e
        *(float2*)(Hout + (b0 + b) * 4096 + hg * 64 + rem) = m;
    }
}

// ---------------------------------------------------------------------------
// Stage 2. Grid 512 = 32 bg (4 b) x 16 og (8 o). Block 256 = 2 ol (4 o) x
// 4 eg (2 e) x 32 hc (16 h). Thread tile 4o x 4b x 2e (float2 over e).
// Lane-traffic 3 B/fma. h-partials combined via LDS [hc][256 out] pitch 264.
// ---------------------------------------------------------------------------
__global__ __launch_bounds__(256, 4) void k_stage2(
    const float* __restrict__ dw,   // [512][128][8]
    const float* __restrict__ Hin,  // [128][512][8]
    float* __restrict__ out)        // [128][128][8]
{
    __shared__ float lds[32 * 264];          // 33.8 KB
    const int t  = threadIdx.x;
    const int ol = t & 1;
    const int eg = (t >> 1) & 3;
    const int hc = t >> 3;
    const int bg = blockIdx.x & 31;
    const int og = blockIdx.x >> 5;
    const int b0 = bg * 4;
    const int o0 = og * 8 + ol * 4;
    const int e0 = eg * 2;
    const int h0 = hc * 16;

    float2 acc[4][4];                        // [oo][bb]
    #pragma unroll
    for (int oo = 0; oo < 4; ++oo)
        #pragma unroll
        for (int bb = 0; bb < 4; ++bb)
            acc[oo][bb] = make_float2(1.0f, 1.0f);

    const float* pd = dw + h0 * 1024 + o0 * 8 + e0;
    const float* ph = Hin + b0 * 4096 + h0 * 8 + e0;

    #pragma unroll 4
    for (int ii = 0; ii < 16; ++ii) {
        float2 dv[4], hv[4];
        #pragma unroll
        for (int oo = 0; oo < 4; ++oo) dv[oo] = *(const float2*)(pd + oo * 8);
        #pragma unroll
        for (int bb = 0; bb < 4; ++bb) hv[bb] = *(const float2*)(ph + bb * 4096);
        pd += 1024; ph += 8;
        #pragma unroll
        for (int oo = 0; oo < 4; ++oo)
            #pragma unroll
            for (int bb = 0; bb < 4; ++bb)
                acc[oo][bb] = f2mul(acc[oo][bb], f2nfma1(dv[oo], hv[bb]));
    }

    // partials -> LDS: out = bb*64 + oloc*8 + e  (oloc = ol*4+oo in [0,8))
    #pragma unroll
    for (int oo = 0; oo < 4; ++oo) {
        #pragma unroll
        for (int bb = 0; bb < 4; ++bb) {
            const int o_l = ol * 4 + oo;
            const int idx = bb * 64 + o_l * 8 + e0;
            *(float2*)&lds[hc * 264 + idx] = acc[oo][bb];
        }
    }
    __syncthreads();

    // combine 32 hc, 256 outs -> 1 per thread; contiguous store
    {
        float m = lds[t];
        #pragma unroll
        for (int c = 1; c < 32; ++c)
            m *= lds[c * 264 + t];
        out[(b0 + (t >> 6)) * 1024 + og * 64 + (t & 63)] = 1.0f - m;
    }
}

extern "C" void kernel_launch(void* const* d_in, const int* in_sizes, int n_in,
                              void* d_out, int out_size, void* d_ws, size_t ws_size,
                              hipStream_t stream)
{
    const float* in = (const float*)d_in[0];   // [128][256][8]
    const float* cw = (const float*)d_in[1];   // [256][512][8]
    const float* cs = (const float*)d_in[2];   // [256][512][8]
    const float* dw = (const float*)d_in[3];   // [512][128][8]
    float* outp = (float*)d_out;               // [128][128][8]
    float* H    = (float*)d_ws;                // 2 MB used

    k_stage1<<<1024, 256, 0, stream>>>(in, cw, cs, H);
    k_stage2<<<512, 256, 0, stream>>>(dw, H, outp);
}